// Round 2
// baseline (982.873 us; speedup 1.0000x reference)
//
#include <hip/hip_runtime.h>

#define TSZ (1u << 19)
#define HPRIME 2654435761u

typedef short bf16x8 __attribute__((ext_vector_type(8)));
typedef float f32x4 __attribute__((ext_vector_type(4)));

__device__ __forceinline__ float sigmoidf(float x) {
    return 1.0f / (1.0f + __expf(-x));
}

__device__ __forceinline__ unsigned short f2b(float f) {
    union { float f; unsigned u; } v; v.f = f;
    return (unsigned short)((v.u + 0x7FFFu + ((v.u >> 16) & 1u)) >> 16);
}

__device__ __forceinline__ unsigned f2b_pack(float a, float b) {
    union { float f; unsigned u; } x, y; x.f = a; y.f = b;
    unsigned ra = (x.u + 0x7FFFu + ((x.u >> 16) & 1u)) >> 16;
    unsigned rb = (y.u + 0x7FFFu + ((y.u >> 16) & 1u)) & 0xFFFF0000u;
    return ra | rb;
}

// Swizzled short-index into a wave's 64-row x 64-short LDS region.
// 16B granule g = s>>3 is XORed with row&7: A-frag b128 reads spread 8-way
// across banks (same as the old stride-72 pad) with ZERO pad bytes ->
// 8192 B per wave, 32768 B per block -> 5 blocks/CU.
__device__ __forceinline__ int swz(int row, int s) {
    return (row << 6) + ((((s >> 3) ^ (row & 7)) << 3) | (s & 7));
}

// Precompute B-operand MFMA fragments (bf16):
//  wp2F: Wp2 (64x64), 8 frags (kstep*4+ntile) for layer2
//  wtF : W_tiny cols 1..64 (32x64), 4 frags, K=32
//  wp1F: Wp1 (12x64) K-padded to 32 with zeros, 4 frags, for layer1 MFMA
// B layout for mfma_f32_16x16x32_bf16: lane holds B[k=(lane>>4)*8+j][n=lane&15].
__global__ void repack_frags(const float* __restrict__ Wp2,
                             const float* __restrict__ Wt,
                             const float* __restrict__ Wp1,
                             unsigned short* __restrict__ wp2F,
                             unsigned short* __restrict__ wtF,
                             unsigned short* __restrict__ wp1F) {
    int t = blockIdx.x * blockDim.x + threadIdx.x;
    if (t < 4096) {
        int j = t & 7, lane = (t >> 3) & 63, f = t >> 9;
        int ks = f >> 2, nt = f & 3;
        int k = ks * 32 + (lane >> 4) * 8 + j;
        int n = nt * 16 + (lane & 15);
        wp2F[t] = f2b(Wp2[k * 64 + n]);
    }
    if (t < 2048) {
        int j = t & 7, lane = (t >> 3) & 63, nt = t >> 9;
        int k = (lane >> 4) * 8 + j;
        int n = nt * 16 + (lane & 15);
        wtF[t] = f2b(Wt[k * 65 + 1 + n]);
        // Wp1 frags: zero-pad k >= 12 (guarantees junk in LDS e-rows is harmless)
        wp1F[t] = (k < 12) ? f2b(Wp1[k * 64 + n]) : (unsigned short)0;
    }
}

// Barrier-free; all LDS regions wave-private; DS ops in-order within a wave.
// LDS = 32768 B exactly -> 5 blocks/CU; launch_bounds(256,5) caps VGPR at 102
// so 5 waves/SIMD (62.5% occ) is reachable.
__global__ __launch_bounds__(256, 5)
void sdf_main(const float* __restrict__ in,
              const float* __restrict__ tables,
              const float* __restrict__ Wp3,
              const float* __restrict__ bt,
              const float* __restrict__ Wt,
              const unsigned short* __restrict__ wp2F,
              const unsigned short* __restrict__ wtF,
              const unsigned short* __restrict__ wp1F,
              float* __restrict__ out, int N)
{
    __shared__ __align__(16) unsigned short Abuf[4 * 64 * 64];  // 32768 B

    const int tid = threadIdx.x;
    const int wave = tid >> 6, lane = tid & 63;
    const int quad = lane >> 4, col = lane & 15;
    const long long n0 = (long long)blockIdx.x * 256;
    const int n = (int)n0 + tid;
    const int nc = n < N ? n : N - 1;

    const float px = in[nc * 3 + 0];
    const float py = in[nc * 3 + 1];
    const float pz = in[nc * 3 + 2];

    unsigned short* WB = Abuf + (wave << 12);  // 4096 shorts per wave

    // ---------------- frequency encoding (fp32) ----------------
    const float PIF = 3.14159274101257324e+00f;
    float e[12];
    e[0] = __sinf(px * PIF); e[1]  = __sinf(px * (2.0f * PIF)); e[2]  = __sinf(px * (4.0f * PIF));
    e[3] = __cosf(px * PIF); e[4]  = __cosf(px * (2.0f * PIF)); e[5]  = __cosf(px * (4.0f * PIF));
    e[6] = __sinf(py * PIF); e[7]  = __sinf(py * (2.0f * PIF)); e[8]  = __sinf(py * (4.0f * PIF));
    e[9] = __cosf(py * PIF); e[10] = __cosf(py * (2.0f * PIF)); e[11] = __cosf(py * (4.0f * PIF));

    // ---------------- stage E rows (bf16, K padded to 32) ----------------
    {
        uint4 v0, v1, vz;
        v0.x = f2b_pack(e[0], e[1]);  v0.y = f2b_pack(e[2], e[3]);
        v0.z = f2b_pack(e[4], e[5]);  v0.w = f2b_pack(e[6], e[7]);
        v1.x = f2b_pack(e[8], e[9]);  v1.y = f2b_pack(e[10], e[11]);
        v1.z = 0u; v1.w = 0u;
        vz.x = vz.y = vz.z = vz.w = 0u;
        *reinterpret_cast<uint4*>(WB + swz(lane, 0))  = v0;
        *reinterpret_cast<uint4*>(WB + swz(lane, 8))  = v1;
        *reinterpret_cast<uint4*>(WB + swz(lane, 16)) = vz;
        *reinterpret_cast<uint4*>(WB + swz(lane, 24)) = vz;
    }

    // ---------------- layer1 via MFMA: h = sigmoid(E @ Wp1) ----------------
    // Per mt-tile: read E A-frag (rows mt*16..+15), 4 MFMA, then scatter h
    // (bf16 u16) into the SAME rows (in-order DS: reads precede overwrites).
    {
        bf16x8 w1f[4];
#pragma unroll
        for (int nt = 0; nt < 4; nt++)
            w1f[nt] = *reinterpret_cast<const bf16x8*>(wp1F + (nt * 64 + lane) * 8);
#pragma unroll
        for (int mt = 0; mt < 4; mt++) {
            const bf16x8 ea = *reinterpret_cast<const bf16x8*>(WB + swz(mt * 16 + col, quad * 8));
#pragma unroll
            for (int nt = 0; nt < 4; nt++) {
                f32x4 acc = {0.f, 0.f, 0.f, 0.f};
                acc = __builtin_amdgcn_mfma_f32_16x16x32_bf16(ea, w1f[nt], acc, 0, 0, 0);
#pragma unroll
                for (int r = 0; r < 4; r++) {
                    const int row = mt * 16 + quad * 4 + r;
                    WB[swz(row, nt * 16 + col)] = f2b(sigmoidf(acc[r]));
                }
            }
        }
    }

    // ---------------- layer2 via MFMA + in-register prior ----------------
    float priorMe = 0.f;
    {
        bf16x8 bfr[8];
#pragma unroll
        for (int f = 0; f < 8; f++)
            bfr[f] = *reinterpret_cast<const bf16x8*>(wp2F + (f * 64 + lane) * 8);
        float w3[4];
#pragma unroll
        for (int nt = 0; nt < 4; nt++) w3[nt] = Wp3[nt * 16 + col];

#pragma unroll
        for (int mt = 0; mt < 4; mt++) {
            const int arow = mt * 16 + col;
            const bf16x8 a0 = *reinterpret_cast<const bf16x8*>(WB + swz(arow, quad * 8));
            const bf16x8 a1 = *reinterpret_cast<const bf16x8*>(WB + swz(arow, 32 + quad * 8));
            float pp[4] = {0.f, 0.f, 0.f, 0.f};
#pragma unroll
            for (int nt = 0; nt < 4; nt++) {
                f32x4 acc = {0.f, 0.f, 0.f, 0.f};
                acc = __builtin_amdgcn_mfma_f32_16x16x32_bf16(a0, bfr[nt], acc, 0, 0, 0);
                acc = __builtin_amdgcn_mfma_f32_16x16x32_bf16(a1, bfr[4 + nt], acc, 0, 0, 0);
#pragma unroll
                for (int r = 0; r < 4; r++)
                    pp[r] += w3[nt] * sigmoidf(acc[r]);
            }
#pragma unroll
            for (int r = 0; r < 4; r++) {   // sum over the 16 cols of the group
                pp[r] += __shfl_xor(pp[r], 1, 64);
                pp[r] += __shfl_xor(pp[r], 2, 64);
                pp[r] += __shfl_xor(pp[r], 4, 64);
                pp[r] += __shfl_xor(pp[r], 8, 64);
            }
            // Redistribute in-register: lane L (point L) takes pp[L&3] from
            // quad-group (L>>2)&3. Value is uniform across that group's lanes.
            const int src = ((lane >> 2) & 3) * 16;
            const float t0 = __shfl(pp[0], src, 64);
            const float t1 = __shfl(pp[1], src, 64);
            const float t2 = __shfl(pp[2], src, 64);
            const float t3 = __shfl(pp[3], src, 64);
            const float ta = (lane & 1) ? t1 : t0;
            const float tb = (lane & 1) ? t3 : t2;
            const float sel = (lane & 2) ? tb : ta;
            if ((lane >> 4) == mt) priorMe = sel;
        }
    }

    // ---------------- hash gather, 4-level chunks (explicit MLP) --------------
    const float scl[16] = {15.f, 23.f, 35.f, 53.f, 80.f, 120.5f, 181.25f, 272.375f,
                           409.0625f, 614.09375f, 921.640625f, 1382.9609375f,
                           2074.94140625f, 3112.912109375f, 4669.8681640625f,
                           7005.30224609375f};
    const int ress[10] = {16, 24, 36, 54, 81, 122, 183, 274, 411, 616};
    const float cx = __fadd_rn(__fdiv_rn(px, 30.0f), 0.5f);
    const float cy = __fadd_rn(__fdiv_rn(py, 30.0f), 0.5f);

    float x0 = bt[0];
#pragma unroll
    for (int cc = 0; cc < 4; cc++) {
        float2 q00[4], q10[4], q01[4], q11[4];
        float wxa[4], wya[4];
#pragma unroll
        for (int u = 0; u < 4; u++) {           // issue all 16 loads first
            const int l = cc * 4 + u;
            const float sc = scl[l];
            const float posx = __fadd_rn(__fmul_rn(cx, sc), 0.5f);
            const float posy = __fadd_rn(__fmul_rn(cy, sc), 0.5f);
            const float fx = floorf(posx), fy = floorf(posy);
            wxa[u] = __fsub_rn(posx, fx);
            wya[u] = __fsub_rn(posy, fy);
            const int ix = (int)fx, iy = (int)fy;
            const float* tbl = tables + (size_t)l * (size_t)(TSZ * 2);
            int i00, i10, i01, i11;
            if (l < 10) {
                const int r = ress[l];
                i00 = ix + iy * r; i10 = i00 + 1; i01 = i00 + r; i11 = i01 + 1;
            } else {
                const unsigned ux = (unsigned)ix, uy = (unsigned)iy;
                const unsigned hy0 = uy * HPRIME, hy1 = (uy + 1u) * HPRIME;
                i00 = (int)((ux ^ hy0) & (TSZ - 1u));
                i10 = (int)(((ux + 1u) ^ hy0) & (TSZ - 1u));
                i01 = (int)((ux ^ hy1) & (TSZ - 1u));
                i11 = (int)(((ux + 1u) ^ hy1) & (TSZ - 1u));
            }
            q00[u] = *(const float2*)(tbl + 2 * i00);
            q10[u] = *(const float2*)(tbl + 2 * i10);
            q01[u] = *(const float2*)(tbl + 2 * i01);
            q11[u] = *(const float2*)(tbl + 2 * i11);
        }
        unsigned pk[4];
#pragma unroll
        for (int u = 0; u < 4; u++) {           // then consume
            const int l = cc * 4 + u;
            const float wx = wxa[u], wy = wya[u];
            const float omx = 1.0f - wx, omy = 1.0f - wy;
            const float f0 = (q00[u].x * omx + q10[u].x * wx) * omy +
                             (q01[u].x * omx + q11[u].x * wx) * wy;
            const float f1 = (q00[u].y * omx + q10[u].y * wx) * omy +
                             (q01[u].y * omx + q11[u].y * wx) * wy;
            x0 += f0 * Wt[(2 * l) * 65] + f1 * Wt[(2 * l + 1) * 65];
            pk[u] = f2b_pack(f0, f1);
        }
        uint4 v; v.x = pk[0]; v.y = pk[1]; v.z = pk[2]; v.w = pk[3];
        *reinterpret_cast<uint4*>(WB + swz(lane, cc * 8)) = v;   // feat row overlay
    }

    // ---------------- epilogue: W_tiny MFMA, direct global stores --------------
    {
        bf16x8 fa[4];
#pragma unroll
        for (int mt = 0; mt < 4; mt++)
            fa[mt] = *reinterpret_cast<const bf16x8*>(WB + swz(mt * 16 + col, quad * 8));
        bf16x8 wb[4];
        float bb[4];
#pragma unroll
        for (int nt = 0; nt < 4; nt++) {
            wb[nt] = *reinterpret_cast<const bf16x8*>(wtF + (nt * 64 + lane) * 8);
            bb[nt] = bt[1 + nt * 16 + col];
        }
        const long long wbase = n0 + (long long)wave * 64;
        float* op = out + (size_t)wbase * 65;
        const bool full = (wbase + 64 <= (long long)N);
#pragma unroll
        for (int mt = 0; mt < 4; mt++) {
#pragma unroll
            for (int nt = 0; nt < 4; nt++) {
                f32x4 acc = {0.f, 0.f, 0.f, 0.f};
                acc = __builtin_amdgcn_mfma_f32_16x16x32_bf16(fa[mt], wb[nt], acc, 0, 0, 0);
                if (full) {
#pragma unroll
                    for (int r = 0; r < 4; r++)
                        op[(mt * 16 + quad * 4 + r) * 65 + 1 + nt * 16 + col] = acc[r] + bb[nt];
                } else {
#pragma unroll
                    for (int r = 0; r < 4; r++) {
                        const int row = mt * 16 + quad * 4 + r;
                        if (wbase + row < (long long)N)
                            op[(size_t)row * 65 + 1 + nt * 16 + col] = acc[r] + bb[nt];
                    }
                }
            }
        }
        if (n < N) out[(size_t)n * 65] = pz - x0 - priorMe;
    }
}

extern "C" void kernel_launch(void* const* d_in, const int* in_sizes, int n_in,
                              void* d_out, int out_size, void* d_ws, size_t ws_size,
                              hipStream_t stream) {
    const float* inputs = (const float*)d_in[0];
    const float* tables = (const float*)d_in[1];
    const float* W_tiny = (const float*)d_in[2];
    const float* b_tiny = (const float*)d_in[3];
    const float* Wp1    = (const float*)d_in[4];
    const float* Wp2    = (const float*)d_in[5];
    const float* Wp3    = (const float*)d_in[6];
    float* out = (float*)d_out;
    unsigned short* wp2F = (unsigned short*)d_ws;        // 4096 bf16
    unsigned short* wtF  = wp2F + 4096;                  // 2048 bf16
    unsigned short* wp1F = wtF + 2048;                   // 2048 bf16

    const int N = in_sizes[0] / 3;

    hipLaunchKernelGGL(repack_frags, dim3(16), dim3(256), 0, stream,
                       Wp2, W_tiny, Wp1, wp2F, wtF, wp1F);

    const int grid = (N + 255) / 256;
    hipLaunchKernelGGL(sdf_main, dim3(grid), dim3(256), 0, stream,
                       inputs, tables, Wp3, b_tiny, W_tiny, wp2F, wtF, wp1F, out, N);
}

// Round 3
// 863.020 us; speedup vs baseline: 1.1389x; 1.1389x over previous
//
#include <hip/hip_runtime.h>

#define TSZ (1u << 19)
#define HPRIME 2654435761u

typedef short bf16x8 __attribute__((ext_vector_type(8)));
typedef float f32x4 __attribute__((ext_vector_type(4)));

__device__ __forceinline__ float sigmoidf(float x) {
    return 1.0f / (1.0f + __expf(-x));
}

__device__ __forceinline__ unsigned short f2b(float f) {
    union { float f; unsigned u; } v; v.f = f;
    return (unsigned short)((v.u + 0x7FFFu + ((v.u >> 16) & 1u)) >> 16);
}

__device__ __forceinline__ unsigned f2b_pack(float a, float b) {
    union { float f; unsigned u; } x, y; x.f = a; y.f = b;
    unsigned ra = (x.u + 0x7FFFu + ((x.u >> 16) & 1u)) >> 16;
    unsigned rb = (y.u + 0x7FFFu + ((y.u >> 16) & 1u)) & 0xFFFF0000u;
    return ra | rb;
}

// Swizzled short-index into a wave's 64-row x 64-short LDS region.
// 16B granule g = s>>3 is XORed with row&7: A-frag b128 reads spread 8-way
// across banks with zero pad bytes.
__device__ __forceinline__ int swz(int row, int s) {
    return (row << 6) + ((((s >> 3) ^ (row & 7)) << 3) | (s & 7));
}

// Precompute B-operand MFMA fragments (bf16):
//  wp2F: Wp2 (64x64), 8 frags (kstep*4+ntile) for layer2
//  wtF : W_tiny cols 1..64 (32x64), 4 frags, K=32
//  wp1F: Wp1 (12x64) K-padded to 32 with zeros, 4 frags, for layer1 MFMA
// B layout for mfma_f32_16x16x32_bf16: lane holds B[k=(lane>>4)*8+j][n=lane&15].
__global__ void repack_frags(const float* __restrict__ Wp2,
                             const float* __restrict__ Wt,
                             const float* __restrict__ Wp1,
                             unsigned short* __restrict__ wp2F,
                             unsigned short* __restrict__ wtF,
                             unsigned short* __restrict__ wp1F) {
    int t = blockIdx.x * blockDim.x + threadIdx.x;
    if (t < 4096) {
        int j = t & 7, lane = (t >> 3) & 63, f = t >> 9;
        int ks = f >> 2, nt = f & 3;
        int k = ks * 32 + (lane >> 4) * 8 + j;
        int n = nt * 16 + (lane & 15);
        wp2F[t] = f2b(Wp2[k * 64 + n]);
    }
    if (t < 2048) {
        int j = t & 7, lane = (t >> 3) & 63, nt = t >> 9;
        int k = (lane >> 4) * 8 + j;
        int n = nt * 16 + (lane & 15);
        wtF[t] = f2b(Wt[k * 65 + 1 + n]);
        wp1F[t] = (k < 12) ? f2b(Wp1[k * 64 + n]) : (unsigned short)0;
    }
}

// Barrier-free; all LDS regions wave-private; DS ops in-order within a wave.
// LDS deliberately padded to 40960 B: 163840/40960 = 4 blocks/CU EXACTLY.
// R2 showed the 5th block/CU is traffic-negative (L2 thrash: FETCH +157MB,
// WRITE +132MB with identical store code) -> cap concurrency at 4, spend the
// VGPR headroom (launch_bounds(256,4) -> 128) on gather MLP instead.
__global__ __launch_bounds__(256, 4)
void sdf_main(const float* __restrict__ in,
              const float* __restrict__ tables,
              const float* __restrict__ Wp3,
              const float* __restrict__ bt,
              const float* __restrict__ Wt,
              const unsigned short* __restrict__ wp2F,
              const unsigned short* __restrict__ wtF,
              const unsigned short* __restrict__ wp1F,
              float* __restrict__ out, int N)
{
    __shared__ __align__(16) unsigned short Abuf[4 * 64 * 80];  // 40960 B

    const int tid = threadIdx.x;
    const int wave = tid >> 6, lane = tid & 63;
    const int quad = lane >> 4, col = lane & 15;
    const long long n0 = (long long)blockIdx.x * 256;
    const int n = (int)n0 + tid;
    const int nc = n < N ? n : N - 1;

    const float px = in[nc * 3 + 0];
    const float py = in[nc * 3 + 1];
    const float pz = in[nc * 3 + 2];

    unsigned short* WB = Abuf + wave * 5120;  // 10240 B per wave (top 2KB pad)

    // ---------------- frequency encoding (fp32) ----------------
    const float PIF = 3.14159274101257324e+00f;
    float e[12];
    e[0] = __sinf(px * PIF); e[1]  = __sinf(px * (2.0f * PIF)); e[2]  = __sinf(px * (4.0f * PIF));
    e[3] = __cosf(px * PIF); e[4]  = __cosf(px * (2.0f * PIF)); e[5]  = __cosf(px * (4.0f * PIF));
    e[6] = __sinf(py * PIF); e[7]  = __sinf(py * (2.0f * PIF)); e[8]  = __sinf(py * (4.0f * PIF));
    e[9] = __cosf(py * PIF); e[10] = __cosf(py * (2.0f * PIF)); e[11] = __cosf(py * (4.0f * PIF));

    // ---------------- stage E rows (bf16, K padded to 32) ----------------
    {
        uint4 v0, v1, vz;
        v0.x = f2b_pack(e[0], e[1]);  v0.y = f2b_pack(e[2], e[3]);
        v0.z = f2b_pack(e[4], e[5]);  v0.w = f2b_pack(e[6], e[7]);
        v1.x = f2b_pack(e[8], e[9]);  v1.y = f2b_pack(e[10], e[11]);
        v1.z = 0u; v1.w = 0u;
        vz.x = vz.y = vz.z = vz.w = 0u;
        *reinterpret_cast<uint4*>(WB + swz(lane, 0))  = v0;
        *reinterpret_cast<uint4*>(WB + swz(lane, 8))  = v1;
        *reinterpret_cast<uint4*>(WB + swz(lane, 16)) = vz;
        *reinterpret_cast<uint4*>(WB + swz(lane, 24)) = vz;
    }

    // ---------------- layer1 via MFMA: h = sigmoid(E @ Wp1) ----------------
    {
        bf16x8 w1f[4];
#pragma unroll
        for (int nt = 0; nt < 4; nt++)
            w1f[nt] = *reinterpret_cast<const bf16x8*>(wp1F + (nt * 64 + lane) * 8);
#pragma unroll
        for (int mt = 0; mt < 4; mt++) {
            const bf16x8 ea = *reinterpret_cast<const bf16x8*>(WB + swz(mt * 16 + col, quad * 8));
#pragma unroll
            for (int nt = 0; nt < 4; nt++) {
                f32x4 acc = {0.f, 0.f, 0.f, 0.f};
                acc = __builtin_amdgcn_mfma_f32_16x16x32_bf16(ea, w1f[nt], acc, 0, 0, 0);
#pragma unroll
                for (int r = 0; r < 4; r++) {
                    const int row = mt * 16 + quad * 4 + r;
                    WB[swz(row, nt * 16 + col)] = f2b(sigmoidf(acc[r]));
                }
            }
        }
    }

    // ---------------- layer2 via MFMA + in-register prior ----------------
    float priorMe = 0.f;
    {
        bf16x8 bfr[8];
#pragma unroll
        for (int f = 0; f < 8; f++)
            bfr[f] = *reinterpret_cast<const bf16x8*>(wp2F + (f * 64 + lane) * 8);
        float w3[4];
#pragma unroll
        for (int nt = 0; nt < 4; nt++) w3[nt] = Wp3[nt * 16 + col];

#pragma unroll
        for (int mt = 0; mt < 4; mt++) {
            const int arow = mt * 16 + col;
            const bf16x8 a0 = *reinterpret_cast<const bf16x8*>(WB + swz(arow, quad * 8));
            const bf16x8 a1 = *reinterpret_cast<const bf16x8*>(WB + swz(arow, 32 + quad * 8));
            float pp[4] = {0.f, 0.f, 0.f, 0.f};
#pragma unroll
            for (int nt = 0; nt < 4; nt++) {
                f32x4 acc = {0.f, 0.f, 0.f, 0.f};
                acc = __builtin_amdgcn_mfma_f32_16x16x32_bf16(a0, bfr[nt], acc, 0, 0, 0);
                acc = __builtin_amdgcn_mfma_f32_16x16x32_bf16(a1, bfr[4 + nt], acc, 0, 0, 0);
#pragma unroll
                for (int r = 0; r < 4; r++)
                    pp[r] += w3[nt] * sigmoidf(acc[r]);
            }
#pragma unroll
            for (int r = 0; r < 4; r++) {   // sum over the 16 cols of the group
                pp[r] += __shfl_xor(pp[r], 1, 64);
                pp[r] += __shfl_xor(pp[r], 2, 64);
                pp[r] += __shfl_xor(pp[r], 4, 64);
                pp[r] += __shfl_xor(pp[r], 8, 64);
            }
            // lane L takes pp[L&3] from quad-group (L>>2)&3 (uniform there).
            const int src = ((lane >> 2) & 3) * 16;
            const float t0 = __shfl(pp[0], src, 64);
            const float t1 = __shfl(pp[1], src, 64);
            const float t2 = __shfl(pp[2], src, 64);
            const float t3 = __shfl(pp[3], src, 64);
            const float ta = (lane & 1) ? t1 : t0;
            const float tb = (lane & 1) ? t3 : t2;
            const float sel = (lane & 2) ? tb : ta;
            if ((lane >> 4) == mt) priorMe = sel;
        }
    }

    // ---------------- hash gather, 4-level chunks (explicit MLP) --------------
    const float scl[16] = {15.f, 23.f, 35.f, 53.f, 80.f, 120.5f, 181.25f, 272.375f,
                           409.0625f, 614.09375f, 921.640625f, 1382.9609375f,
                           2074.94140625f, 3112.912109375f, 4669.8681640625f,
                           7005.30224609375f};
    const int ress[10] = {16, 24, 36, 54, 81, 122, 183, 274, 411, 616};
    const float cx = __fadd_rn(__fdiv_rn(px, 30.0f), 0.5f);
    const float cy = __fadd_rn(__fdiv_rn(py, 30.0f), 0.5f);

    float x0 = bt[0];
#pragma unroll
    for (int cc = 0; cc < 4; cc++) {
        float2 q00[4], q10[4], q01[4], q11[4];
        float wxa[4], wya[4];
#pragma unroll
        for (int u = 0; u < 4; u++) {           // issue all 16 loads first
            const int l = cc * 4 + u;
            const float sc = scl[l];
            const float posx = __fadd_rn(__fmul_rn(cx, sc), 0.5f);
            const float posy = __fadd_rn(__fmul_rn(cy, sc), 0.5f);
            const float fx = floorf(posx), fy = floorf(posy);
            wxa[u] = __fsub_rn(posx, fx);
            wya[u] = __fsub_rn(posy, fy);
            const int ix = (int)fx, iy = (int)fy;
            const float* tbl = tables + (size_t)l * (size_t)(TSZ * 2);
            int i00, i10, i01, i11;
            if (l < 10) {
                const int r = ress[l];
                i00 = ix + iy * r; i10 = i00 + 1; i01 = i00 + r; i11 = i01 + 1;
            } else {
                const unsigned ux = (unsigned)ix, uy = (unsigned)iy;
                const unsigned hy0 = uy * HPRIME, hy1 = (uy + 1u) * HPRIME;
                i00 = (int)((ux ^ hy0) & (TSZ - 1u));
                i10 = (int)(((ux + 1u) ^ hy0) & (TSZ - 1u));
                i01 = (int)((ux ^ hy1) & (TSZ - 1u));
                i11 = (int)(((ux + 1u) ^ hy1) & (TSZ - 1u));
            }
            q00[u] = *(const float2*)(tbl + 2 * i00);
            q10[u] = *(const float2*)(tbl + 2 * i10);
            q01[u] = *(const float2*)(tbl + 2 * i01);
            q11[u] = *(const float2*)(tbl + 2 * i11);
        }
        unsigned pk[4];
#pragma unroll
        for (int u = 0; u < 4; u++) {           // then consume
            const int l = cc * 4 + u;
            const float wx = wxa[u], wy = wya[u];
            const float omx = 1.0f - wx, omy = 1.0f - wy;
            const float f0 = (q00[u].x * omx + q10[u].x * wx) * omy +
                             (q01[u].x * omx + q11[u].x * wx) * wy;
            const float f1 = (q00[u].y * omx + q10[u].y * wx) * omy +
                             (q01[u].y * omx + q11[u].y * wx) * wy;
            x0 += f0 * Wt[(2 * l) * 65] + f1 * Wt[(2 * l + 1) * 65];
            pk[u] = f2b_pack(f0, f1);
        }
        uint4 v; v.x = pk[0]; v.y = pk[1]; v.z = pk[2]; v.w = pk[3];
        *reinterpret_cast<uint4*>(WB + swz(lane, cc * 8)) = v;   // feat row overlay
    }

    // ---------------- epilogue: W_tiny MFMA, row-clustered global stores ------
    // Per mt-tile: compute all 4 nt accumulators FIRST, then store row-major so
    // each row's four 64B segments (bytes 4..260 of the 260B row) are issued
    // back-to-back, and this tile's col-0 dwords land in the same window
    // (lane>>4 == mt). Rows become fully dirty in L2 within a few instructions
    // -> full-line evictions instead of the 1.4-1.6x write amplification seen
    // with r-interleaved stores.
    {
        bf16x8 fa[4];
#pragma unroll
        for (int mt = 0; mt < 4; mt++)
            fa[mt] = *reinterpret_cast<const bf16x8*>(WB + swz(mt * 16 + col, quad * 8));
        bf16x8 wb[4];
        float bb[4];
#pragma unroll
        for (int nt = 0; nt < 4; nt++) {
            wb[nt] = *reinterpret_cast<const bf16x8*>(wtF + (nt * 64 + lane) * 8);
            bb[nt] = bt[1 + nt * 16 + col];
        }
        const long long wbase = n0 + (long long)wave * 64;
        float* op = out + (size_t)wbase * 65;
        const bool full = (wbase + 64 <= (long long)N);
        const float c0 = pz - x0 - priorMe;    // col0 of row `lane` (point n)
#pragma unroll
        for (int mt = 0; mt < 4; mt++) {
            f32x4 acc[4];
#pragma unroll
            for (int nt = 0; nt < 4; nt++) {
                f32x4 a = {0.f, 0.f, 0.f, 0.f};
                acc[nt] = __builtin_amdgcn_mfma_f32_16x16x32_bf16(fa[mt], wb[nt], a, 0, 0, 0);
            }
            if (full) {
#pragma unroll
                for (int r = 0; r < 4; r++) {
                    float* rp = op + (size_t)(mt * 16 + quad * 4 + r) * 65;
#pragma unroll
                    for (int nt = 0; nt < 4; nt++)
                        rp[1 + nt * 16 + col] = acc[nt][r] + bb[nt];
                }
                if ((lane >> 4) == mt) op[(size_t)lane * 65] = c0;
            } else {
#pragma unroll
                for (int r = 0; r < 4; r++) {
                    const int row = mt * 16 + quad * 4 + r;
                    if (wbase + row < (long long)N) {
                        float* rp = op + (size_t)row * 65;
#pragma unroll
                        for (int nt = 0; nt < 4; nt++)
                            rp[1 + nt * 16 + col] = acc[nt][r] + bb[nt];
                    }
                }
                if ((lane >> 4) == mt && n < N) op[(size_t)lane * 65] = c0;
            }
        }
    }
}

extern "C" void kernel_launch(void* const* d_in, const int* in_sizes, int n_in,
                              void* d_out, int out_size, void* d_ws, size_t ws_size,
                              hipStream_t stream) {
    const float* inputs = (const float*)d_in[0];
    const float* tables = (const float*)d_in[1];
    const float* W_tiny = (const float*)d_in[2];
    const float* b_tiny = (const float*)d_in[3];
    const float* Wp1    = (const float*)d_in[4];
    const float* Wp2    = (const float*)d_in[5];
    const float* Wp3    = (const float*)d_in[6];
    float* out = (float*)d_out;
    unsigned short* wp2F = (unsigned short*)d_ws;        // 4096 bf16
    unsigned short* wtF  = wp2F + 4096;                  // 2048 bf16
    unsigned short* wp1F = wtF + 2048;                   // 2048 bf16

    const int N = in_sizes[0] / 3;

    hipLaunchKernelGGL(repack_frags, dim3(16), dim3(256), 0, stream,
                       Wp2, W_tiny, Wp1, wp2F, wtF, wp1F);

    const int grid = (N + 255) / 256;
    hipLaunchKernelGGL(sdf_main, dim3(grid), dim3(256), 0, stream,
                       inputs, tables, Wp3, b_tiny, W_tiny, wp2F, wtF, wp1F, out, N);
}